// Round 1
// baseline (136.238 us; speedup 1.0000x reference)
//
#include <hip/hip_runtime.h>
#include <math.h>

#define D_MODEL 768
#define D_STATE 64
#define BATCH   2
#define SEQ     2048
#define M_TOTAL (BATCH * SEQ)   // 4096

typedef unsigned short ushort_t;
typedef float f32x4 __attribute__((ext_vector_type(4)));
typedef __bf16 bf16x8 __attribute__((ext_vector_type(8)));

__device__ __forceinline__ ushort_t f2bf(float f) {
    unsigned u = __float_as_uint(f);
    u = (u + 0x7FFFu + ((u >> 16) & 1u)) >> 16;   // RNE
    return (ushort_t)u;
}

__device__ __forceinline__ void gload16(const void* g, void* shm) {
    __builtin_amdgcn_global_load_lds(
        (const __attribute__((address_space(1))) void*)g,
        (__attribute__((address_space(3))) void*)shm, 16, 0, 0);
}

// ---------------- fused pre-kernel: LayerNorm->bf16 (blocks 0..1023) + weight casts (blocks 1024..2175) ----------------
__global__ __launch_bounds__(256) void pre_kernel(const float* __restrict__ x,
                                                  const float* __restrict__ gamma,
                                                  const float* __restrict__ beta,
                                                  ushort_t* __restrict__ xnb,
                                                  const float* __restrict__ W_in,
                                                  const float* __restrict__ W_out,
                                                  ushort_t* __restrict__ Winb,
                                                  ushort_t* __restrict__ Woutb) {
    int bx = blockIdx.x;
    if (bx >= 1024) {
        int b2 = bx - 1024;                    // 0..1151
        const float* src = (b2 < 576) ? W_in : W_out;
        ushort_t*    dst = (b2 < 576) ? Winb : Woutb;
        int blk = (b2 < 576) ? b2 : b2 - 576;
        int i = (blk * 256 + threadIdx.x) * 4;
        float4 v = *(const float4*)(src + i);
        ushort4 o = make_ushort4(f2bf(v.x), f2bf(v.y), f2bf(v.z), f2bf(v.w));
        *(ushort4*)(dst + i) = o;
        return;
    }
    int row  = bx * 4 + (threadIdx.x >> 6);
    int lane = threadIdx.x & 63;
    const float* xr = x + (size_t)row * D_MODEL;
    float4 v[3];
    v[0] = *(const float4*)(xr + lane * 4);
    v[1] = *(const float4*)(xr + 256 + lane * 4);
    v[2] = *(const float4*)(xr + 512 + lane * 4);
    float s = 0.f, ss = 0.f;
#pragma unroll
    for (int i = 0; i < 3; ++i) {
        s  += v[i].x + v[i].y + v[i].z + v[i].w;
        ss += v[i].x * v[i].x + v[i].y * v[i].y + v[i].z * v[i].z + v[i].w * v[i].w;
    }
#pragma unroll
    for (int off = 1; off < 64; off <<= 1) {
        s  += __shfl_xor(s, off, 64);
        ss += __shfl_xor(ss, off, 64);
    }
    float mean = s * (1.0f / 768.0f);
    float var  = ss * (1.0f / 768.0f) - mean * mean;
    float inv  = 1.0f / sqrtf(var + 1e-5f);
    ushort_t* xo = xnb + (size_t)row * D_MODEL;
#pragma unroll
    for (int i = 0; i < 3; ++i) {
        int c = i * 256 + lane * 4;
        float4 g  = *(const float4*)(gamma + c);
        float4 bb = *(const float4*)(beta + c);
        ushort4 o = make_ushort4(f2bf((v[i].x - mean) * inv * g.x + bb.x),
                                 f2bf((v[i].y - mean) * inv * g.y + bb.y),
                                 f2bf((v[i].z - mean) * inv * g.z + bb.z),
                                 f2bf((v[i].w - mean) * inv * g.w + bb.w));
        *(ushort4*)(xo + c) = o;
    }
}

// ---------------- bf16 MFMA GEMM, 128x96 tile, BK=64, 4 waves x (64x48) ----------------
// LDS rows = 128 B (64 bf16) = 8 segs of 16B; seg sg of row r stored at
// slot (sg ^ (r&7)) -> all fragment ds_read_b128 and staging are bank-optimal.
// A tile 128x64 bf16 @ smem[0..16K), B tile 96x64 bf16 @ smem[16K..28K).
// grid = (M/128, N/96) = (32, 8) = 256 blocks = 1/CU.

// gemm_in: u = xn @ W_in^T + b_in -> uTb bf16 [b][n][s] (LDS-transposed epilogue)
__global__ __launch_bounds__(256) void gemm_in(const ushort_t* __restrict__ A,   // xn bf16 [4096][768]
                                               const ushort_t* __restrict__ B,   // W_in bf16 [768][768]
                                               const float* __restrict__ bias,
                                               ushort_t* __restrict__ uTb) {     // bf16 [2][768][2048]
    __shared__ __align__(16) char smem[28672];
    float* T = (float*)smem;                 // epilogue alias (48x128 fp32 = 24576 B)

    int tid = threadIdx.x;
    int w = tid >> 6, l = tid & 63;
    int bm = blockIdx.x * 128, bn = blockIdx.y * 96;
    int wr = w >> 1, wc = w & 1;

    float biasv[3];
#pragma unroll
    for (int nt = 0; nt < 3; ++nt)
        biasv[nt] = bias[bn + wc * 48 + nt * 16 + (l & 15)];

    int lr = l >> 3;                 // staging sub-row 0..7
    int scol0 = ((l & 7) ^ lr) * 8;  // pre-swizzled k-offset (row&7 == lr always)

    f32x4 acc[4][3] = {};
    for (int k0 = 0; k0 < D_MODEL; k0 += 64) {
#pragma unroll
        for (int q = 0; q < 4; ++q) {
            int row = w * 32 + q * 8 + lr;
            gload16(A + (size_t)(bm + row) * D_MODEL + k0 + scol0, smem + w * 4096 + q * 1024);
        }
#pragma unroll
        for (int q = 0; q < 3; ++q) {
            int row = w * 24 + q * 8 + lr;
            gload16(B + (size_t)(bn + row) * D_MODEL + k0 + scol0, smem + 16384 + w * 3072 + q * 1024);
        }
        __syncthreads();
#pragma unroll
        for (int kk = 0; kk < 2; ++kk) {
            int seg = kk * 4 + (l >> 4);
            bf16x8 af[4], bf[3];
#pragma unroll
            for (int mt = 0; mt < 4; ++mt) {
                int r = wr * 64 + mt * 16 + (l & 15);
                af[mt] = *(const bf16x8*)(smem + r * 128 + ((seg ^ (r & 7)) * 16));
            }
#pragma unroll
            for (int nt = 0; nt < 3; ++nt) {
                int r = wc * 48 + nt * 16 + (l & 15);
                bf[nt] = *(const bf16x8*)(smem + 16384 + r * 128 + ((seg ^ (r & 7)) * 16));
            }
#pragma unroll
            for (int mt = 0; mt < 4; ++mt)
#pragma unroll
                for (int nt = 0; nt < 3; ++nt)
                    acc[mt][nt] = __builtin_amdgcn_mfma_f32_16x16x32_bf16(af[mt], bf[nt], acc[mt][nt], 0, 0, 0);
        }
        __syncthreads();
    }

    // epilogue: two 48-n halves; T[n][m] fp32 with XOR-swizzled 16B segs
    int b = bm >> 11, sbase = bm & 2047;
#pragma unroll
    for (int h = 0; h < 2; ++h) {
        if (wc == h) {
#pragma unroll
            for (int nt = 0; nt < 3; ++nt) {
                int n = nt * 16 + (l & 15);      // 0..47 within half
                float bv = biasv[nt];
#pragma unroll
                for (int mt = 0; mt < 4; ++mt) {
                    int seg = wr * 16 + mt * 4 + (l >> 4);   // m/4, 0..31
                    f32x4 v = acc[mt][nt];
                    v.x += bv; v.y += bv; v.z += bv; v.w += bv;
                    *(f32x4*)(T + n * 128 + ((seg ^ (n & 7)) * 4)) = v;
                }
            }
        }
        __syncthreads();
        if (tid < 192) {
            int n2 = tid >> 2;            // 0..47
            int m0 = (tid & 3) * 32;      // 0..96
            ushort_t* dst = uTb + ((size_t)b * D_MODEL + bn + h * 48 + n2) * SEQ + sbase + m0;
#pragma unroll
            for (int q = 0; q < 8; ++q) {
                int seg = (m0 >> 2) + q;
                f32x4 v = *(const f32x4*)(T + n2 * 128 + ((seg ^ (n2 & 7)) * 4));
                ushort4 o = make_ushort4(f2bf(v.x), f2bf(v.y), f2bf(v.z), f2bf(v.w));
                *(ushort4*)(dst + q * 4) = o;
            }
        }
        __syncthreads();
    }
}

// gemm_out: out = y @ W_out^T + b_out + resid, natural [m][n] fp32 store
__global__ __launch_bounds__(256) void gemm_out(const ushort_t* __restrict__ A,   // y bf16 [4096][768]
                                                const ushort_t* __restrict__ B,   // W_out bf16 [768][768]
                                                const float* __restrict__ bias,
                                                const float* __restrict__ resid,
                                                float* __restrict__ out) {
    __shared__ __align__(16) char smem[28672];
    int tid = threadIdx.x;
    int w = tid >> 6, l = tid & 63;
    int bm = blockIdx.x * 128, bn = blockIdx.y * 96;
    int wr = w >> 1, wc = w & 1;

    float biasv[3];
#pragma unroll
    for (int nt = 0; nt < 3; ++nt)
        biasv[nt] = bias[bn + wc * 48 + nt * 16 + (l & 15)];

    int lr = l >> 3;
    int scol0 = ((l & 7) ^ lr) * 8;

    f32x4 acc[4][3] = {};
    for (int k0 = 0; k0 < D_MODEL; k0 += 64) {
#pragma unroll
        for (int q = 0; q < 4; ++q) {
            int row = w * 32 + q * 8 + lr;
            gload16(A + (size_t)(bm + row) * D_MODEL + k0 + scol0, smem + w * 4096 + q * 1024);
        }
#pragma unroll
        for (int q = 0; q < 3; ++q) {
            int row = w * 24 + q * 8 + lr;
            gload16(B + (size_t)(bn + row) * D_MODEL + k0 + scol0, smem + 16384 + w * 3072 + q * 1024);
        }
        __syncthreads();
#pragma unroll
        for (int kk = 0; kk < 2; ++kk) {
            int seg = kk * 4 + (l >> 4);
            bf16x8 af[4], bf[3];
#pragma unroll
            for (int mt = 0; mt < 4; ++mt) {
                int r = wr * 64 + mt * 16 + (l & 15);
                af[mt] = *(const bf16x8*)(smem + r * 128 + ((seg ^ (r & 7)) * 16));
            }
#pragma unroll
            for (int nt = 0; nt < 3; ++nt) {
                int r = wc * 48 + nt * 16 + (l & 15);
                bf[nt] = *(const bf16x8*)(smem + 16384 + r * 128 + ((seg ^ (r & 7)) * 16));
            }
#pragma unroll
            for (int mt = 0; mt < 4; ++mt)
#pragma unroll
                for (int nt = 0; nt < 3; ++nt)
                    acc[mt][nt] = __builtin_amdgcn_mfma_f32_16x16x32_bf16(af[mt], bf[nt], acc[mt][nt], 0, 0, 0);
        }
        __syncthreads();
    }
#pragma unroll
    for (int mt = 0; mt < 4; ++mt)
#pragma unroll
        for (int i = 0; i < 4; ++i) {
            int m = bm + wr * 64 + mt * 16 + (l >> 4) * 4 + i;
            const float* rp = resid + (size_t)m * D_MODEL + bn;
            float* op = out + (size_t)m * D_MODEL + bn;
#pragma unroll
            for (int nt = 0; nt < 3; ++nt) {
                int nl = wc * 48 + nt * 16 + (l & 15);
                op[nl] = acc[mt][nt][i] + biasv[nt] + rp[nl];
            }
        }
}

// ---------------- scan as blocked matmuls (SSD-style) ----------------
#define OFF_U  0
#define OFF_V  9216
#define OFF_T  18432
#define OFF_M  27648
#define OFF_H  36864
#define OFF_W  46080
#define OFF_SM 63488

__global__ __launch_bounds__(256) void scan_mm(const ushort_t* __restrict__ uTb,
                                               const float* __restrict__ log_A,
                                               const float* __restrict__ B_p,
                                               const float* __restrict__ C_p,
                                               const float* __restrict__ D_p,
                                               const float* __restrict__ log_dt,
                                               ushort_t* __restrict__ yTb) {
    __shared__ __align__(16) char smem[65024];
    ushort_t* Up = (ushort_t*)(smem + OFF_U);
    ushort_t* Vp = (ushort_t*)(smem + OFF_V);
    ushort_t* Tp = (ushort_t*)(smem + OFF_T);
    ushort_t* Mp = (ushort_t*)(smem + OFF_M);
    ushort_t* Hp = (ushort_t*)(smem + OFF_H);
    float*    Wp = (float*)(smem + OFF_W);
    float*    Kp = (float*)(smem + OFF_W);
    float*    aArr  = (float*)(smem + OFF_SM);
    float*    BbArr = aArr + 64;
    float*    CcArr = aArr + 128;
    float*    CBArr = aArr + 192;
    float*    Kc    = aArr + 256;

    int d   = blockIdx.x;
    int tid = threadIdx.x;
    int w   = tid >> 6, l = tid & 63;

    if (tid < 64) {
        int n = tid;
        float dt = __expf(log_dt[d]);
        float a  = -dt * __expf(log_A[d * 64 + n]);
        float Bb = B_p[d * 64 + n] * dt;
        float Cc = C_p[d * 64 + n];
        aArr[n] = a; BbArr[n] = Bb; CcArr[n] = Cc; CBArr[n] = Cc * Bb;
    }
    __syncthreads();

    {
        int tau = tid & 63, part = tid >> 6;
        float s = 0.f;
#pragma unroll
        for (int i = 0; i < 16; ++i) {
            int n = part * 16 + i;
            s += CBArr[n] * __expf((float)tau * aArr[n]);
        }
        Kp[part * 64 + tau] = s;
    }
    __syncthreads();
    if (tid < 64)
        Kc[tid] = Kp[tid] + Kp[64 + tid] + Kp[128 + tid] + Kp[192 + tid]
                + (tid == 0 ? D_p[d] : 0.f);
    __syncthreads();

    {
        int r = tid >> 2, seg = (tid & 3) * 16;
        float a = aArr[r], Bb = BbArr[r];
#pragma unroll
        for (int i = 0; i < 16; ++i) {
            int s = seg + i;
            Vp[r * 72 + s] = f2bf(Bb * __expf((float)(63 - s) * a));
        }
#pragma unroll
        for (int i = 0; i < 16; ++i) {
            int n = seg + i;
            Mp[r * 72 + n] = f2bf(CcArr[n] * __expf((float)(r + 1) * aArr[n]));
        }
#pragma unroll
        for (int i = 0; i < 16; ++i) {
            int s = seg + i;
            Tp[r * 72 + s] = (s <= r) ? f2bf(Kc[r - s]) : (ushort_t)0;
        }
        int col = r, bu = col >> 5, cu = col & 31;
        const ushort_t* usrc = uTb + ((size_t)bu * D_MODEL + d) * SEQ + cu * 64 + seg;
        *(uint4*)(Up + col * 72 + seg)     = *(const uint4*)(usrc);
        *(uint4*)(Up + col * 72 + seg + 8) = *(const uint4*)(usrc + 8);
    }
    __syncthreads();

    {
        int p0 = w * 16;
        f32x4 acc1[4] = {};
#pragma unroll
        for (int kk = 0; kk < 2; ++kk) {
            int koff = kk * 32 + (l >> 4) * 8;
            bf16x8 af = *(const bf16x8*)(Vp + (p0 + (l & 15)) * 72 + koff);
#pragma unroll
            for (int qt = 0; qt < 4; ++qt) {
                bf16x8 bf = *(const bf16x8*)(Up + (qt * 16 + (l & 15)) * 72 + koff);
                acc1[qt] = __builtin_amdgcn_mfma_f32_16x16x32_bf16(af, bf, acc1[qt], 0, 0, 0);
            }
        }
#pragma unroll
        for (int qt = 0; qt < 4; ++qt)
#pragma unroll
            for (int i = 0; i < 4; ++i)
                Wp[(qt * 16 + (l & 15)) * 68 + p0 + (l >> 4) * 4 + i] = acc1[qt][i];
    }
    __syncthreads();

    if (tid < 128) {
        int b2 = tid >> 6, n = tid & 63;
        float Ab64 = __expf(64.f * aArr[n]);
        float H = 0.f;
#pragma unroll
        for (int c = 0; c < 32; ++c) {
            int col = b2 * 32 + c;
            Hp[col * 72 + n] = f2bf(H);
            H = fmaf(Ab64, H, Wp[col * 68 + n]);
        }
    }
    __syncthreads();

    {
        int j0 = w * 16;
        f32x4 accY[4] = {};
#pragma unroll
        for (int kk = 0; kk < 2; ++kk) {
            int koff = kk * 32 + (l >> 4) * 8;
            bf16x8 at = *(const bf16x8*)(Tp + (j0 + (l & 15)) * 72 + koff);
            bf16x8 am = *(const bf16x8*)(Mp + (j0 + (l & 15)) * 72 + koff);
#pragma unroll
            for (int qt = 0; qt < 4; ++qt) {
                bf16x8 bu = *(const bf16x8*)(Up + (qt * 16 + (l & 15)) * 72 + koff);
                bf16x8 bh = *(const bf16x8*)(Hp + (qt * 16 + (l & 15)) * 72 + koff);
                accY[qt] = __builtin_amdgcn_mfma_f32_16x16x32_bf16(at, bu, accY[qt], 0, 0, 0);
                accY[qt] = __builtin_amdgcn_mfma_f32_16x16x32_bf16(am, bh, accY[qt], 0, 0, 0);
            }
        }
#pragma unroll
        for (int qt = 0; qt < 4; ++qt)
#pragma unroll
            for (int i = 0; i < 4; ++i)
                Wp[(qt * 16 + (l & 15)) * 68 + j0 + (l >> 4) * 4 + i] = accY[qt][i];
    }
    __syncthreads();

    {
        int col = tid >> 2, jseg = (tid & 3) * 16;
        int b3 = col >> 5, c3 = col & 31;
        ushort_t* dst = yTb + ((size_t)b3 * D_MODEL + d) * SEQ + c3 * 64 + jseg;
#pragma unroll
        for (int q = 0; q < 4; ++q) {
            f32x4 v = *(const f32x4*)(Wp + col * 68 + jseg + q * 4);
            ushort4 o = make_ushort4(f2bf(v.x), f2bf(v.y), f2bf(v.z), f2bf(v.w));
            *(ushort4*)(dst + q * 4) = o;
        }
    }
}

// ---------------- transpose: yTb bf16 [2][768][2048] -> yA bf16 [4096][768] ----------------
__global__ __launch_bounds__(256) void tcast_kernel(const ushort_t* __restrict__ yTb,
                                                    ushort_t* __restrict__ yA) {
    __shared__ ushort_t T2[64 * 72];
    int t = threadIdx.x;
    int s0 = blockIdx.x * 64, d0 = blockIdx.y * 64, b = blockIdx.z;
    int dl = t >> 2, sq = (t & 3) * 16;
    const ushort_t* src = yTb + ((size_t)b * D_MODEL + d0 + dl) * SEQ + s0 + sq;
    uint4 v01 = *(const uint4*)(src);
    uint4 v23 = *(const uint4*)(src + 8);
    const ushort_t* pv = (const ushort_t*)&v01;
#pragma unroll
    for (int j = 0; j < 8; ++j) T2[(sq + j) * 72 + dl] = pv[j];
    pv = (const ushort_t*)&v23;
#pragma unroll
    for (int j = 0; j < 8; ++j) T2[(sq + 8 + j) * 72 + dl] = pv[j];
    __syncthreads();
    int sl = t >> 2, dseg = (t & 3) * 16;
    ushort_t* dst = yA + ((size_t)(b * SEQ + s0 + sl)) * D_MODEL + d0 + dseg;
    *(uint4*)(dst)     = *(const uint4*)&T2[sl * 72 + dseg];
    *(uint4*)(dst + 8) = *(const uint4*)&T2[sl * 72 + dseg + 8];
}

extern "C" void kernel_launch(void* const* d_in, const int* in_sizes, int n_in,
                              void* d_out, int out_size, void* d_ws, size_t ws_size,
                              hipStream_t stream) {
    const float* x        = (const float*)d_in[0];
    const float* ln_gamma = (const float*)d_in[1];
    const float* ln_beta  = (const float*)d_in[2];
    const float* W_in     = (const float*)d_in[3];
    const float* b_in     = (const float*)d_in[4];
    const float* log_A    = (const float*)d_in[5];
    const float* B_p      = (const float*)d_in[6];
    const float* C_p      = (const float*)d_in[7];
    const float* D_p      = (const float*)d_in[8];
    const float* log_dt   = (const float*)d_in[9];
    const float* W_out    = (const float*)d_in[10];
    const float* b_out    = (const float*)d_in[11];
    float* out = (float*)d_out;

    char* ws = (char*)d_ws;
    ushort_t* uTb   = (ushort_t*)(ws + 0);                    // 6291456 B
    ushort_t* yTb   = (ushort_t*)(ws + 6291456);              // 6291456 B
    ushort_t* xnb   = (ushort_t*)(ws + 12582912);             // 6291456 B (reused as yA)
    ushort_t* yA    = xnb;
    ushort_t* Winb  = (ushort_t*)(ws + 18874368);             // 1179648 B
    ushort_t* Woutb = (ushort_t*)(ws + 20054016);             // 1179648 B

    pre_kernel<<<dim3(1024 + 1152), 256, 0, stream>>>(x, ln_gamma, ln_beta, xnb,
                                                      W_in, W_out, Winb, Woutb);
    gemm_in<<<dim3(M_TOTAL / 128, D_MODEL / 96), 256, 0, stream>>>(xnb, Winb, b_in, uTb);
    scan_mm<<<dim3(D_MODEL), 256, 0, stream>>>(uTb, log_A, B_p, C_p, D_p, log_dt, yTb);
    tcast_kernel<<<dim3(SEQ / 64, D_MODEL / 64, BATCH), 256, 0, stream>>>(yTb, yA);
    gemm_out<<<dim3(M_TOTAL / 128, D_MODEL / 96), 256, 0, stream>>>(yA, Woutb, b_out, x, out);
}

// Round 2
// 126.199 us; speedup vs baseline: 1.0795x; 1.0795x over previous
//
#include <hip/hip_runtime.h>
#include <math.h>

#define D_MODEL 768
#define D_STATE 64
#define BATCH   2
#define SEQ     2048
#define M_TOTAL (BATCH * SEQ)   // 4096

typedef unsigned short ushort_t;
typedef float f32x4 __attribute__((ext_vector_type(4)));
typedef __bf16 bf16x8 __attribute__((ext_vector_type(8)));

__device__ __forceinline__ ushort_t f2bf(float f) {
    unsigned u = __float_as_uint(f);
    u = (u + 0x7FFFu + ((u >> 16) & 1u)) >> 16;   // RNE
    return (ushort_t)u;
}

__device__ __forceinline__ float bf2f(ushort_t b) {
    return __uint_as_float(((unsigned)b) << 16);
}

__device__ __forceinline__ void gload16(const void* g, void* shm) {
    __builtin_amdgcn_global_load_lds(
        (const __attribute__((address_space(1))) void*)g,
        (__attribute__((address_space(3))) void*)shm, 16, 0, 0);
}

// ---------------- fused pre-kernel: LayerNorm->bf16 (blocks 0..1023) + weight casts (blocks 1024..2175) ----------------
__global__ __launch_bounds__(256) void pre_kernel(const float* __restrict__ x,
                                                  const float* __restrict__ gamma,
                                                  const float* __restrict__ beta,
                                                  ushort_t* __restrict__ xnb,
                                                  const float* __restrict__ W_in,
                                                  const float* __restrict__ W_out,
                                                  ushort_t* __restrict__ Winb,
                                                  ushort_t* __restrict__ Woutb) {
    int bx = blockIdx.x;
    if (bx >= 1024) {
        int b2 = bx - 1024;                    // 0..1151
        const float* src = (b2 < 576) ? W_in : W_out;
        ushort_t*    dst = (b2 < 576) ? Winb : Woutb;
        int blk = (b2 < 576) ? b2 : b2 - 576;
        int i = (blk * 256 + threadIdx.x) * 4;
        float4 v = *(const float4*)(src + i);
        ushort4 o = make_ushort4(f2bf(v.x), f2bf(v.y), f2bf(v.z), f2bf(v.w));
        *(ushort4*)(dst + i) = o;
        return;
    }
    int row  = bx * 4 + (threadIdx.x >> 6);
    int lane = threadIdx.x & 63;
    const float* xr = x + (size_t)row * D_MODEL;
    float4 v[3];
    v[0] = *(const float4*)(xr + lane * 4);
    v[1] = *(const float4*)(xr + 256 + lane * 4);
    v[2] = *(const float4*)(xr + 512 + lane * 4);
    float s = 0.f, ss = 0.f;
#pragma unroll
    for (int i = 0; i < 3; ++i) {
        s  += v[i].x + v[i].y + v[i].z + v[i].w;
        ss += v[i].x * v[i].x + v[i].y * v[i].y + v[i].z * v[i].z + v[i].w * v[i].w;
    }
#pragma unroll
    for (int off = 1; off < 64; off <<= 1) {
        s  += __shfl_xor(s, off, 64);
        ss += __shfl_xor(ss, off, 64);
    }
    float mean = s * (1.0f / 768.0f);
    float var  = ss * (1.0f / 768.0f) - mean * mean;
    float inv  = 1.0f / sqrtf(var + 1e-5f);
    ushort_t* xo = xnb + (size_t)row * D_MODEL;
#pragma unroll
    for (int i = 0; i < 3; ++i) {
        int c = i * 256 + lane * 4;
        float4 g  = *(const float4*)(gamma + c);
        float4 bb = *(const float4*)(beta + c);
        ushort4 o = make_ushort4(f2bf((v[i].x - mean) * inv * g.x + bb.x),
                                 f2bf((v[i].y - mean) * inv * g.y + bb.y),
                                 f2bf((v[i].z - mean) * inv * g.z + bb.z),
                                 f2bf((v[i].w - mean) * inv * g.w + bb.w));
        *(ushort4*)(xo + c) = o;
    }
}

// ---------------- bf16 MFMA GEMM, 64x96 tile, BK=128, 4 waves (2x2) each 32x48 ----------------
// Same proven LDS layout as the 128.3us baseline: 256B rows (16 segs of 16B),
// seg sg of row r stored at slot (sg ^ (r&7)); global_load_lds staging with
// pre-swizzled global source column. grid = (64, 8) = 512 blocks = 2/CU so the
// wave-level overlap across co-resident blocks (the thing R1 broke) is kept.
// A tile 64x128 @ smem[0..16K), B tile 96x128 @ smem[16K..40K).

// gemm_in: u = xn @ W_in^T + b_in -> uTb bf16 [b][n][s] (LDS-transposed epilogue)
__global__ __launch_bounds__(256) void gemm_in(const ushort_t* __restrict__ A,   // xn bf16 [4096][768]
                                               const ushort_t* __restrict__ B,   // W_in bf16 [768][768]
                                               const float* __restrict__ bias,
                                               ushort_t* __restrict__ uTb) {     // bf16 [2][768][2048]
    __shared__ __align__(16) char smem[40960];
    float* T = (float*)smem;                 // epilogue alias (96x68 fp32 = 26112 B)

    int tid = threadIdx.x;
    int w = tid >> 6, l = tid & 63;
    int bm = blockIdx.x * 64, bn = blockIdx.y * 96;
    int wr = w >> 1, wc = w & 1;

    int rowq = l >> 4;         // 0..3
    int segq = l & 15;         // 0..15

    float biasv[3];
#pragma unroll
    for (int nt = 0; nt < 3; ++nt)
        biasv[nt] = bias[bn + wc * 48 + nt * 16 + (l & 15)];

    f32x4 acc[2][3] = {};
    for (int k0 = 0; k0 < D_MODEL; k0 += 128) {
#pragma unroll
        for (int q = 0; q < 4; ++q) {
            int row = w * 16 + q * 4 + rowq;
            int col = k0 + ((segq ^ (row & 7)) * 8);
            gload16(A + (size_t)(bm + row) * D_MODEL + col, smem + w * 4096 + q * 1024);
        }
#pragma unroll
        for (int q = 0; q < 6; ++q) {
            int row = w * 24 + q * 4 + rowq;
            int col = k0 + ((segq ^ (row & 7)) * 8);
            gload16(B + (size_t)(bn + row) * D_MODEL + col, smem + 16384 + w * 6144 + q * 1024);
        }
        __syncthreads();
#pragma unroll
        for (int kk = 0; kk < 4; ++kk) {
            int sgb = kk * 4 + (l >> 4);
            bf16x8 af[2], bf[3];
#pragma unroll
            for (int mt = 0; mt < 2; ++mt) {
                int r = wr * 32 + mt * 16 + (l & 15);
                af[mt] = *(const bf16x8*)(smem + r * 256 + ((sgb ^ (r & 7)) * 16));
            }
#pragma unroll
            for (int nt = 0; nt < 3; ++nt) {
                int r = wc * 48 + nt * 16 + (l & 15);
                bf[nt] = *(const bf16x8*)(smem + 16384 + r * 256 + ((sgb ^ (r & 7)) * 16));
            }
#pragma unroll
            for (int mt = 0; mt < 2; ++mt)
#pragma unroll
                for (int nt = 0; nt < 3; ++nt)
                    acc[mt][nt] = __builtin_amdgcn_mfma_f32_16x16x32_bf16(af[mt], bf[nt], acc[mt][nt], 0, 0, 0);
        }
        __syncthreads();
    }
    // epilogue: LDS transpose -> uTb[b][n][s] bf16 coalesced
#pragma unroll
    for (int mt = 0; mt < 2; ++mt)
#pragma unroll
        for (int nt = 0; nt < 3; ++nt)
#pragma unroll
            for (int i = 0; i < 4; ++i) {
                int nl = wc * 48 + nt * 16 + (l & 15);
                int ml = wr * 32 + mt * 16 + (l >> 4) * 4 + i;
                T[nl * 68 + ml] = acc[mt][nt][i] + biasv[nt];
            }
    __syncthreads();
    int b = bm >> 11, sbase = bm & 2047;
    for (int t2 = tid; t2 < 384; t2 += 256) {
        int n2 = t2 >> 2, m0 = (t2 & 3) * 16;
        ushort_t* dst = uTb + ((size_t)b * D_MODEL + bn + n2) * SEQ + sbase + m0;
#pragma unroll
        for (int q = 0; q < 4; ++q) {
            float4 v = *(const float4*)&T[n2 * 68 + m0 + q * 4];
            ushort4 o = make_ushort4(f2bf(v.x), f2bf(v.y), f2bf(v.z), f2bf(v.w));
            *(ushort4*)(dst + q * 4) = o;
        }
    }
}

// gemm_out: out = y @ W_out^T + b_out + resid, natural [m][n] fp32 store
__global__ __launch_bounds__(256) void gemm_out(const ushort_t* __restrict__ A,   // y bf16 [4096][768]
                                                const ushort_t* __restrict__ B,   // W_out bf16 [768][768]
                                                const float* __restrict__ bias,
                                                const float* __restrict__ resid,
                                                float* __restrict__ out) {
    __shared__ __align__(16) char smem[40960];
    int tid = threadIdx.x;
    int w = tid >> 6, l = tid & 63;
    int bm = blockIdx.x * 64, bn = blockIdx.y * 96;
    int wr = w >> 1, wc = w & 1;

    int rowq = l >> 4;
    int segq = l & 15;

    float biasv[3];
#pragma unroll
    for (int nt = 0; nt < 3; ++nt)
        biasv[nt] = bias[bn + wc * 48 + nt * 16 + (l & 15)];

    f32x4 acc[2][3] = {};
    for (int k0 = 0; k0 < D_MODEL; k0 += 128) {
#pragma unroll
        for (int q = 0; q < 4; ++q) {
            int row = w * 16 + q * 4 + rowq;
            int col = k0 + ((segq ^ (row & 7)) * 8);
            gload16(A + (size_t)(bm + row) * D_MODEL + col, smem + w * 4096 + q * 1024);
        }
#pragma unroll
        for (int q = 0; q < 6; ++q) {
            int row = w * 24 + q * 4 + rowq;
            int col = k0 + ((segq ^ (row & 7)) * 8);
            gload16(B + (size_t)(bn + row) * D_MODEL + col, smem + 16384 + w * 6144 + q * 1024);
        }
        __syncthreads();
#pragma unroll
        for (int kk = 0; kk < 4; ++kk) {
            int sgb = kk * 4 + (l >> 4);
            bf16x8 af[2], bf[3];
#pragma unroll
            for (int mt = 0; mt < 2; ++mt) {
                int r = wr * 32 + mt * 16 + (l & 15);
                af[mt] = *(const bf16x8*)(smem + r * 256 + ((sgb ^ (r & 7)) * 16));
            }
#pragma unroll
            for (int nt = 0; nt < 3; ++nt) {
                int r = wc * 48 + nt * 16 + (l & 15);
                bf[nt] = *(const bf16x8*)(smem + 16384 + r * 256 + ((sgb ^ (r & 7)) * 16));
            }
#pragma unroll
            for (int mt = 0; mt < 2; ++mt)
#pragma unroll
                for (int nt = 0; nt < 3; ++nt)
                    acc[mt][nt] = __builtin_amdgcn_mfma_f32_16x16x32_bf16(af[mt], bf[nt], acc[mt][nt], 0, 0, 0);
        }
        __syncthreads();
    }
#pragma unroll
    for (int mt = 0; mt < 2; ++mt)
#pragma unroll
        for (int i = 0; i < 4; ++i) {
            int m = bm + wr * 32 + mt * 16 + (l >> 4) * 4 + i;
            const float* rp = resid + (size_t)m * D_MODEL + bn;
            float* op = out + (size_t)m * D_MODEL + bn;
#pragma unroll
            for (int nt = 0; nt < 3; ++nt) {
                int nl = wc * 48 + nt * 16 + (l & 15);
                op[nl] = acc[mt][nt][i] + biasv[nt] + rp[nl];
            }
        }
}

// ---------------- scan as blocked matmuls (SSD-style) ----------------
#define OFF_U  0
#define OFF_V  9216
#define OFF_T  18432
#define OFF_M  27648
#define OFF_H  36864
#define OFF_W  46080
#define OFF_SM 63488

__global__ __launch_bounds__(256) void scan_mm(const ushort_t* __restrict__ uTb,
                                               const float* __restrict__ log_A,
                                               const float* __restrict__ B_p,
                                               const float* __restrict__ C_p,
                                               const float* __restrict__ D_p,
                                               const float* __restrict__ log_dt,
                                               ushort_t* __restrict__ yTb) {
    __shared__ __align__(16) char smem[65024];
    ushort_t* Up = (ushort_t*)(smem + OFF_U);
    ushort_t* Vp = (ushort_t*)(smem + OFF_V);
    ushort_t* Tp = (ushort_t*)(smem + OFF_T);
    ushort_t* Mp = (ushort_t*)(smem + OFF_M);
    ushort_t* Hp = (ushort_t*)(smem + OFF_H);
    float*    Wp = (float*)(smem + OFF_W);
    float*    Kp = (float*)(smem + OFF_W);
    float*    aArr  = (float*)(smem + OFF_SM);
    float*    BbArr = aArr + 64;
    float*    CcArr = aArr + 128;
    float*    CBArr = aArr + 192;
    float*    Kc    = aArr + 256;

    int d   = blockIdx.x;
    int tid = threadIdx.x;
    int w   = tid >> 6, l = tid & 63;

    if (tid < 64) {
        int n = tid;
        float dt = __expf(log_dt[d]);
        float a  = -dt * __expf(log_A[d * 64 + n]);
        float Bb = B_p[d * 64 + n] * dt;
        float Cc = C_p[d * 64 + n];
        aArr[n] = a; BbArr[n] = Bb; CcArr[n] = Cc; CBArr[n] = Cc * Bb;
    }
    __syncthreads();

    {
        int tau = tid & 63, part = tid >> 6;
        float s = 0.f;
#pragma unroll
        for (int i = 0; i < 16; ++i) {
            int n = part * 16 + i;
            s += CBArr[n] * __expf((float)tau * aArr[n]);
        }
        Kp[part * 64 + tau] = s;
    }
    __syncthreads();
    if (tid < 64)
        Kc[tid] = Kp[tid] + Kp[64 + tid] + Kp[128 + tid] + Kp[192 + tid]
                + (tid == 0 ? D_p[d] : 0.f);
    __syncthreads();

    {
        int r = tid >> 2, seg = (tid & 3) * 16;
        float a = aArr[r], Bb = BbArr[r];
#pragma unroll
        for (int i = 0; i < 16; ++i) {
            int s = seg + i;
            Vp[r * 72 + s] = f2bf(Bb * __expf((float)(63 - s) * a));
        }
#pragma unroll
        for (int i = 0; i < 16; ++i) {
            int n = seg + i;
            Mp[r * 72 + n] = f2bf(CcArr[n] * __expf((float)(r + 1) * aArr[n]));
        }
#pragma unroll
        for (int i = 0; i < 16; ++i) {
            int s = seg + i;
            Tp[r * 72 + s] = (s <= r) ? f2bf(Kc[r - s]) : (ushort_t)0;
        }
        int col = r, bu = col >> 5, cu = col & 31;
        const ushort_t* usrc = uTb + ((size_t)bu * D_MODEL + d) * SEQ + cu * 64 + seg;
        *(uint4*)(Up + col * 72 + seg)     = *(const uint4*)(usrc);
        *(uint4*)(Up + col * 72 + seg + 8) = *(const uint4*)(usrc + 8);
    }
    __syncthreads();

    {
        int p0 = w * 16;
        f32x4 acc1[4] = {};
#pragma unroll
        for (int kk = 0; kk < 2; ++kk) {
            int koff = kk * 32 + (l >> 4) * 8;
            bf16x8 af = *(const bf16x8*)(Vp + (p0 + (l & 15)) * 72 + koff);
#pragma unroll
            for (int qt = 0; qt < 4; ++qt) {
                bf16x8 bf = *(const bf16x8*)(Up + (qt * 16 + (l & 15)) * 72 + koff);
                acc1[qt] = __builtin_amdgcn_mfma_f32_16x16x32_bf16(af, bf, acc1[qt], 0, 0, 0);
            }
        }
#pragma unroll
        for (int qt = 0; qt < 4; ++qt)
#pragma unroll
            for (int i = 0; i < 4; ++i)
                Wp[(qt * 16 + (l & 15)) * 68 + p0 + (l >> 4) * 4 + i] = acc1[qt][i];
    }
    __syncthreads();

    if (tid < 128) {
        int b2 = tid >> 6, n = tid & 63;
        float Ab64 = __expf(64.f * aArr[n]);
        float H = 0.f;
#pragma unroll
        for (int c = 0; c < 32; ++c) {
            int col = b2 * 32 + c;
            Hp[col * 72 + n] = f2bf(H);
            H = fmaf(Ab64, H, Wp[col * 68 + n]);
        }
    }
    __syncthreads();

    {
        int j0 = w * 16;
        f32x4 accY[4] = {};
#pragma unroll
        for (int kk = 0; kk < 2; ++kk) {
            int koff = kk * 32 + (l >> 4) * 8;
            bf16x8 at = *(const bf16x8*)(Tp + (j0 + (l & 15)) * 72 + koff);
            bf16x8 am = *(const bf16x8*)(Mp + (j0 + (l & 15)) * 72 + koff);
#pragma unroll
            for (int qt = 0; qt < 4; ++qt) {
                bf16x8 bu = *(const bf16x8*)(Up + (qt * 16 + (l & 15)) * 72 + koff);
                bf16x8 bh = *(const bf16x8*)(Hp + (qt * 16 + (l & 15)) * 72 + koff);
                accY[qt] = __builtin_amdgcn_mfma_f32_16x16x32_bf16(at, bu, accY[qt], 0, 0, 0);
                accY[qt] = __builtin_amdgcn_mfma_f32_16x16x32_bf16(am, bh, accY[qt], 0, 0, 0);
            }
        }
#pragma unroll
        for (int qt = 0; qt < 4; ++qt)
#pragma unroll
            for (int i = 0; i < 4; ++i)
                Wp[(qt * 16 + (l & 15)) * 68 + j0 + (l >> 4) * 4 + i] = accY[qt][i];
    }
    __syncthreads();

    {
        int col = tid >> 2, jseg = (tid & 3) * 16;
        int b3 = col >> 5, c3 = col & 31;
        ushort_t* dst = yTb + ((size_t)b3 * D_MODEL + d) * SEQ + c3 * 64 + jseg;
#pragma unroll
        for (int q = 0; q < 4; ++q) {
            f32x4 v = *(const f32x4*)(Wp + col * 68 + jseg + q * 4);
            ushort4 o = make_ushort4(f2bf(v.x), f2bf(v.y), f2bf(v.z), f2bf(v.w));
            *(ushort4*)(dst + q * 4) = o;
        }
    }
}

// ---------------- transpose: yTb bf16 [2][768][2048] -> yA bf16 [4096][768] ----------------
// bf16 global IO, fp32 LDS staging (same bank behavior as the proven fp32 tcast)
__global__ __launch_bounds__(256) void tcast_kernel(const ushort_t* __restrict__ yTb,
                                                    ushort_t* __restrict__ yA) {
    __shared__ float T2[64 * 68];
    int t = threadIdx.x;
    int s0 = blockIdx.x * 64, d0 = blockIdx.y * 64, b = blockIdx.z;
    int dl = t >> 2, sq = (t & 3) * 16;
    const ushort_t* src = yTb + ((size_t)b * D_MODEL + d0 + dl) * SEQ + s0 + sq;
    uint4 v01 = *(const uint4*)(src);
    uint4 v23 = *(const uint4*)(src + 8);
    const ushort_t* pv = (const ushort_t*)&v01;
#pragma unroll
    for (int j = 0; j < 8; ++j) T2[(sq + j) * 68 + dl] = bf2f(pv[j]);
    pv = (const ushort_t*)&v23;
#pragma unroll
    for (int j = 0; j < 8; ++j) T2[(sq + 8 + j) * 68 + dl] = bf2f(pv[j]);
    __syncthreads();
    int sl = t >> 2, dseg = (t & 3) * 16;
    ushort_t* dst = yA + ((size_t)(b * SEQ + s0 + sl)) * D_MODEL + d0 + dseg;
#pragma unroll
    for (int q = 0; q < 4; ++q) {
        float4 v = *(const float4*)&T2[sl * 68 + dseg + q * 4];
        ushort4 o = make_ushort4(f2bf(v.x), f2bf(v.y), f2bf(v.z), f2bf(v.w));
        *(ushort4*)(dst + q * 4) = o;
    }
}

extern "C" void kernel_launch(void* const* d_in, const int* in_sizes, int n_in,
                              void* d_out, int out_size, void* d_ws, size_t ws_size,
                              hipStream_t stream) {
    const float* x        = (const float*)d_in[0];
    const float* ln_gamma = (const float*)d_in[1];
    const float* ln_beta  = (const float*)d_in[2];
    const float* W_in     = (const float*)d_in[3];
    const float* b_in     = (const float*)d_in[4];
    const float* log_A    = (const float*)d_in[5];
    const float* B_p      = (const float*)d_in[6];
    const float* C_p      = (const float*)d_in[7];
    const float* D_p      = (const float*)d_in[8];
    const float* log_dt   = (const float*)d_in[9];
    const float* W_out    = (const float*)d_in[10];
    const float* b_out    = (const float*)d_in[11];
    float* out = (float*)d_out;

    char* ws = (char*)d_ws;
    ushort_t* uTb   = (ushort_t*)(ws + 0);                    // 6291456 B
    ushort_t* yTb   = (ushort_t*)(ws + 6291456);              // 6291456 B
    ushort_t* xnb   = (ushort_t*)(ws + 12582912);             // 6291456 B (reused as yA)
    ushort_t* yA    = xnb;
    ushort_t* Winb  = (ushort_t*)(ws + 18874368);             // 1179648 B
    ushort_t* Woutb = (ushort_t*)(ws + 20054016);             // 1179648 B

    pre_kernel<<<dim3(1024 + 1152), 256, 0, stream>>>(x, ln_gamma, ln_beta, xnb,
                                                      W_in, W_out, Winb, Woutb);
    gemm_in<<<dim3(M_TOTAL / 64, D_MODEL / 96), 256, 0, stream>>>(xnb, Winb, b_in, uTb);
    scan_mm<<<dim3(D_MODEL), 256, 0, stream>>>(uTb, log_A, B_p, C_p, D_p, log_dt, yTb);
    tcast_kernel<<<dim3(SEQ / 64, D_MODEL / 64, BATCH), 256, 0, stream>>>(yTb, yA);
    gemm_out<<<dim3(M_TOTAL / 64, D_MODEL / 96), 256, 0, stream>>>(yA, Woutb, b_out, x, out);
}

// Round 3
// 124.792 us; speedup vs baseline: 1.0917x; 1.0113x over previous
//
#include <hip/hip_runtime.h>
#include <math.h>

#define D_MODEL 768
#define D_STATE 64
#define BATCH   2
#define SEQ     2048
#define M_TOTAL (BATCH * SEQ)   // 4096

typedef unsigned short ushort_t;
typedef float f32x4 __attribute__((ext_vector_type(4)));
typedef __bf16 bf16x8 __attribute__((ext_vector_type(8)));

__device__ __forceinline__ ushort_t f2bf(float f) {
    unsigned u = __float_as_uint(f);
    u = (u + 0x7FFFu + ((u >> 16) & 1u)) >> 16;   // RNE
    return (ushort_t)u;
}

__device__ __forceinline__ float bf2f(ushort_t b) {
    return __uint_as_float(((unsigned)b) << 16);
}

__device__ __forceinline__ void gload16(const void* g, void* shm) {
    __builtin_amdgcn_global_load_lds(
        (const __attribute__((address_space(1))) void*)g,
        (__attribute__((address_space(3))) void*)shm, 16, 0, 0);
}

// ---------------- fused pre-kernel: LayerNorm->bf16 (blocks 0..1023) + weight casts (blocks 1024..2175) ----------------
__global__ __launch_bounds__(256) void pre_kernel(const float* __restrict__ x,
                                                  const float* __restrict__ gamma,
                                                  const float* __restrict__ beta,
                                                  ushort_t* __restrict__ xnb,
                                                  const float* __restrict__ W_in,
                                                  const float* __restrict__ W_out,
                                                  ushort_t* __restrict__ Winb,
                                                  ushort_t* __restrict__ Woutb) {
    int bx = blockIdx.x;
    if (bx >= 1024) {
        int b2 = bx - 1024;                    // 0..1151
        const float* src = (b2 < 576) ? W_in : W_out;
        ushort_t*    dst = (b2 < 576) ? Winb : Woutb;
        int blk = (b2 < 576) ? b2 : b2 - 576;
        int i = (blk * 256 + threadIdx.x) * 4;
        float4 v = *(const float4*)(src + i);
        ushort4 o = make_ushort4(f2bf(v.x), f2bf(v.y), f2bf(v.z), f2bf(v.w));
        *(ushort4*)(dst + i) = o;
        return;
    }
    int row  = bx * 4 + (threadIdx.x >> 6);
    int lane = threadIdx.x & 63;
    const float* xr = x + (size_t)row * D_MODEL;
    float4 v[3];
    v[0] = *(const float4*)(xr + lane * 4);
    v[1] = *(const float4*)(xr + 256 + lane * 4);
    v[2] = *(const float4*)(xr + 512 + lane * 4);
    float s = 0.f, ss = 0.f;
#pragma unroll
    for (int i = 0; i < 3; ++i) {
        s  += v[i].x + v[i].y + v[i].z + v[i].w;
        ss += v[i].x * v[i].x + v[i].y * v[i].y + v[i].z * v[i].z + v[i].w * v[i].w;
    }
#pragma unroll
    for (int off = 1; off < 64; off <<= 1) {
        s  += __shfl_xor(s, off, 64);
        ss += __shfl_xor(ss, off, 64);
    }
    float mean = s * (1.0f / 768.0f);
    float var  = ss * (1.0f / 768.0f) - mean * mean;
    float inv  = 1.0f / sqrtf(var + 1e-5f);
    ushort_t* xo = xnb + (size_t)row * D_MODEL;
#pragma unroll
    for (int i = 0; i < 3; ++i) {
        int c = i * 256 + lane * 4;
        float4 g  = *(const float4*)(gamma + c);
        float4 bb = *(const float4*)(beta + c);
        ushort4 o = make_ushort4(f2bf((v[i].x - mean) * inv * g.x + bb.x),
                                 f2bf((v[i].y - mean) * inv * g.y + bb.y),
                                 f2bf((v[i].z - mean) * inv * g.z + bb.z),
                                 f2bf((v[i].w - mean) * inv * g.w + bb.w));
        *(ushort4*)(xo + c) = o;
    }
}

// ---------------- bf16 MFMA GEMM, 64x96 tile, BK=64, double-buffered 2-phase ----------------
// T3-minimum pipeline: stage tile t+1 into alt buffers, compute tile t, ONE
// __syncthreads() per K-step (its vmcnt(0) drain is cheap because the staging
// latency hid under the MFMA phase). LDS rows = 128 B (8 segs of 16B), seg sg
// of row r at slot (sg ^ (r&7)); staging uses pre-swizzled global source col
// (R1-verified addressing). A buffers 2x8KB @0, B buffers 2x12KB @16K = 40960B.
// grid = (64, 8) = 512 blocks; LDS allows up to 4 blocks/CU.

// gemm_in: u = xn @ W_in^T + b_in -> uTb bf16 [b][n][s] (LDS-transposed epilogue)
__global__ __launch_bounds__(256) void gemm_in(const ushort_t* __restrict__ A,   // xn bf16 [4096][768]
                                               const ushort_t* __restrict__ B,   // W_in bf16 [768][768]
                                               const float* __restrict__ bias,
                                               ushort_t* __restrict__ uTb) {     // bf16 [2][768][2048]
    __shared__ __align__(16) char smem[40960];
    float* T = (float*)smem;                 // epilogue alias (96x68 fp32 = 26112 B)

    int tid = threadIdx.x;
    int w = tid >> 6, l = tid & 63;
    int bm = blockIdx.x * 64, bn = blockIdx.y * 96;
    int wr = w >> 1, wc = w & 1;

    int lr = l >> 3;                  // staging sub-row 0..7
    int scol0 = ((l & 7) ^ lr) * 8;   // pre-swizzled k-offset

    float biasv[3];
#pragma unroll
    for (int nt = 0; nt < 3; ++nt)
        biasv[nt] = bias[bn + wc * 48 + nt * 16 + (l & 15)];

    char* Acur = smem;          char* Aalt = smem + 8192;
    char* Bcur = smem + 16384;  char* Balt = smem + 28672;

    // prologue: stage tile 0
#pragma unroll
    for (int q = 0; q < 2; ++q) {
        int row = w * 16 + q * 8 + lr;
        gload16(A + (size_t)(bm + row) * D_MODEL + scol0, Acur + w * 2048 + q * 1024);
    }
#pragma unroll
    for (int q = 0; q < 3; ++q) {
        int row = w * 24 + q * 8 + lr;
        gload16(B + (size_t)(bn + row) * D_MODEL + scol0, Bcur + w * 3072 + q * 1024);
    }
    __syncthreads();

    f32x4 acc[2][3] = {};
    for (int t = 0; t < 12; ++t) {
        if (t < 11) {
            int k1 = (t + 1) * 64;
#pragma unroll
            for (int q = 0; q < 2; ++q) {
                int row = w * 16 + q * 8 + lr;
                gload16(A + (size_t)(bm + row) * D_MODEL + k1 + scol0, Aalt + w * 2048 + q * 1024);
            }
#pragma unroll
            for (int q = 0; q < 3; ++q) {
                int row = w * 24 + q * 8 + lr;
                gload16(B + (size_t)(bn + row) * D_MODEL + k1 + scol0, Balt + w * 3072 + q * 1024);
            }
        }
#pragma unroll
        for (int kk = 0; kk < 2; ++kk) {
            int sgb = kk * 4 + (l >> 4);
            bf16x8 af[2], bfr[3];
#pragma unroll
            for (int mt = 0; mt < 2; ++mt) {
                int r = wr * 32 + mt * 16 + (l & 15);
                af[mt] = *(const bf16x8*)(Acur + r * 128 + ((sgb ^ (r & 7)) * 16));
            }
#pragma unroll
            for (int nt = 0; nt < 3; ++nt) {
                int r = wc * 48 + nt * 16 + (l & 15);
                bfr[nt] = *(const bf16x8*)(Bcur + r * 128 + ((sgb ^ (r & 7)) * 16));
            }
#pragma unroll
            for (int mt = 0; mt < 2; ++mt)
#pragma unroll
                for (int nt = 0; nt < 3; ++nt)
                    acc[mt][nt] = __builtin_amdgcn_mfma_f32_16x16x32_bf16(af[mt], bfr[nt], acc[mt][nt], 0, 0, 0);
        }
        __syncthreads();
        char* t1 = Acur; Acur = Aalt; Aalt = t1;
        t1 = Bcur; Bcur = Balt; Balt = t1;
    }

    // epilogue: LDS transpose -> uTb[b][n][s] bf16 coalesced
#pragma unroll
    for (int mt = 0; mt < 2; ++mt)
#pragma unroll
        for (int nt = 0; nt < 3; ++nt)
#pragma unroll
            for (int i = 0; i < 4; ++i) {
                int nl = wc * 48 + nt * 16 + (l & 15);
                int ml = wr * 32 + mt * 16 + (l >> 4) * 4 + i;
                T[nl * 68 + ml] = acc[mt][nt][i] + biasv[nt];
            }
    __syncthreads();
    int b = bm >> 11, sbase = bm & 2047;
    for (int t2 = tid; t2 < 384; t2 += 256) {
        int n2 = t2 >> 2, m0 = (t2 & 3) * 16;
        ushort_t* dst = uTb + ((size_t)b * D_MODEL + bn + n2) * SEQ + sbase + m0;
#pragma unroll
        for (int q = 0; q < 4; ++q) {
            float4 v = *(const float4*)&T[n2 * 68 + m0 + q * 4];
            ushort4 o = make_ushort4(f2bf(v.x), f2bf(v.y), f2bf(v.z), f2bf(v.w));
            *(ushort4*)(dst + q * 4) = o;
        }
    }
}

// gemm_out: out = y @ W_out^T + b_out + resid, natural [m][n] fp32 store
__global__ __launch_bounds__(256) void gemm_out(const ushort_t* __restrict__ A,   // y bf16 [4096][768]
                                                const ushort_t* __restrict__ B,   // W_out bf16 [768][768]
                                                const float* __restrict__ bias,
                                                const float* __restrict__ resid,
                                                float* __restrict__ out) {
    __shared__ __align__(16) char smem[40960];
    int tid = threadIdx.x;
    int w = tid >> 6, l = tid & 63;
    int bm = blockIdx.x * 64, bn = blockIdx.y * 96;
    int wr = w >> 1, wc = w & 1;

    int lr = l >> 3;
    int scol0 = ((l & 7) ^ lr) * 8;

    float biasv[3];
#pragma unroll
    for (int nt = 0; nt < 3; ++nt)
        biasv[nt] = bias[bn + wc * 48 + nt * 16 + (l & 15)];

    char* Acur = smem;          char* Aalt = smem + 8192;
    char* Bcur = smem + 16384;  char* Balt = smem + 28672;

#pragma unroll
    for (int q = 0; q < 2; ++q) {
        int row = w * 16 + q * 8 + lr;
        gload16(A + (size_t)(bm + row) * D_MODEL + scol0, Acur + w * 2048 + q * 1024);
    }
#pragma unroll
    for (int q = 0; q < 3; ++q) {
        int row = w * 24 + q * 8 + lr;
        gload16(B + (size_t)(bn + row) * D_MODEL + scol0, Bcur + w * 3072 + q * 1024);
    }
    __syncthreads();

    f32x4 acc[2][3] = {};
    for (int t = 0; t < 12; ++t) {
        if (t < 11) {
            int k1 = (t + 1) * 64;
#pragma unroll
            for (int q = 0; q < 2; ++q) {
                int row = w * 16 + q * 8 + lr;
                gload16(A + (size_t)(bm + row) * D_MODEL + k1 + scol0, Aalt + w * 2048 + q * 1024);
            }
#pragma unroll
            for (int q = 0; q < 3; ++q) {
                int row = w * 24 + q * 8 + lr;
                gload16(B + (size_t)(bn + row) * D_MODEL + k1 + scol0, Balt + w * 3072 + q * 1024);
            }
        }
#pragma unroll
        for (int kk = 0; kk < 2; ++kk) {
            int sgb = kk * 4 + (l >> 4);
            bf16x8 af[2], bfr[3];
#pragma unroll
            for (int mt = 0; mt < 2; ++mt) {
                int r = wr * 32 + mt * 16 + (l & 15);
                af[mt] = *(const bf16x8*)(Acur + r * 128 + ((sgb ^ (r & 7)) * 16));
            }
#pragma unroll
            for (int nt = 0; nt < 3; ++nt) {
                int r = wc * 48 + nt * 16 + (l & 15);
                bfr[nt] = *(const bf16x8*)(Bcur + r * 128 + ((sgb ^ (r & 7)) * 16));
            }
#pragma unroll
            for (int mt = 0; mt < 2; ++mt)
#pragma unroll
                for (int nt = 0; nt < 3; ++nt)
                    acc[mt][nt] = __builtin_amdgcn_mfma_f32_16x16x32_bf16(af[mt], bfr[nt], acc[mt][nt], 0, 0, 0);
        }
        __syncthreads();
        char* t1 = Acur; Acur = Aalt; Aalt = t1;
        t1 = Bcur; Bcur = Balt; Balt = t1;
    }

#pragma unroll
    for (int mt = 0; mt < 2; ++mt)
#pragma unroll
        for (int i = 0; i < 4; ++i) {
            int m = bm + wr * 32 + mt * 16 + (l >> 4) * 4 + i;
            const float* rp = resid + (size_t)m * D_MODEL + bn;
            float* op = out + (size_t)m * D_MODEL + bn;
#pragma unroll
            for (int nt = 0; nt < 3; ++nt) {
                int nl = wc * 48 + nt * 16 + (l & 15);
                op[nl] = acc[mt][nt][i] + biasv[nt] + rp[nl];
            }
        }
}

// ---------------- scan as blocked matmuls (SSD-style) ----------------
#define OFF_U  0
#define OFF_V  9216
#define OFF_T  18432
#define OFF_M  27648
#define OFF_H  36864
#define OFF_W  46080
#define OFF_SM 63488

__global__ __launch_bounds__(256) void scan_mm(const ushort_t* __restrict__ uTb,
                                               const float* __restrict__ log_A,
                                               const float* __restrict__ B_p,
                                               const float* __restrict__ C_p,
                                               const float* __restrict__ D_p,
                                               const float* __restrict__ log_dt,
                                               ushort_t* __restrict__ yTb) {
    __shared__ __align__(16) char smem[65024];
    ushort_t* Up = (ushort_t*)(smem + OFF_U);
    ushort_t* Vp = (ushort_t*)(smem + OFF_V);
    ushort_t* Tp = (ushort_t*)(smem + OFF_T);
    ushort_t* Mp = (ushort_t*)(smem + OFF_M);
    ushort_t* Hp = (ushort_t*)(smem + OFF_H);
    float*    Wp = (float*)(smem + OFF_W);
    float*    Kp = (float*)(smem + OFF_W);
    float*    aArr  = (float*)(smem + OFF_SM);
    float*    BbArr = aArr + 64;
    float*    CcArr = aArr + 128;
    float*    CBArr = aArr + 192;
    float*    Kc    = aArr + 256;

    int d   = blockIdx.x;
    int tid = threadIdx.x;
    int w   = tid >> 6, l = tid & 63;

    // T14 issue-early: U global loads issued at kernel top; HBM latency hides
    // under the exp-heavy setup phases. Consumed (LDS-written) in build phase.
    int r_pre = tid >> 2, seg_pre = (tid & 3) * 16;
    int bu_pre = r_pre >> 5, cu_pre = r_pre & 31;
    const ushort_t* usrc = uTb + ((size_t)bu_pre * D_MODEL + d) * SEQ + cu_pre * 64 + seg_pre;
    uint4 u01 = *(const uint4*)(usrc);
    uint4 u23 = *(const uint4*)(usrc + 8);

    if (tid < 64) {
        int n = tid;
        float dt = __expf(log_dt[d]);
        float a  = -dt * __expf(log_A[d * 64 + n]);
        float Bb = B_p[d * 64 + n] * dt;
        float Cc = C_p[d * 64 + n];
        aArr[n] = a; BbArr[n] = Bb; CcArr[n] = Cc; CBArr[n] = Cc * Bb;
    }
    __syncthreads();

    {
        int tau = tid & 63, part = tid >> 6;
        float s = 0.f;
#pragma unroll
        for (int i = 0; i < 16; ++i) {
            int n = part * 16 + i;
            s += CBArr[n] * __expf((float)tau * aArr[n]);
        }
        Kp[part * 64 + tau] = s;
    }
    __syncthreads();
    if (tid < 64)
        Kc[tid] = Kp[tid] + Kp[64 + tid] + Kp[128 + tid] + Kp[192 + tid]
                + (tid == 0 ? D_p[d] : 0.f);
    __syncthreads();

    {
        int r = tid >> 2, seg = (tid & 3) * 16;
        float a = aArr[r], Bb = BbArr[r];
#pragma unroll
        for (int i = 0; i < 16; ++i) {
            int s = seg + i;
            Vp[r * 72 + s] = f2bf(Bb * __expf((float)(63 - s) * a));
        }
#pragma unroll
        for (int i = 0; i < 16; ++i) {
            int n = seg + i;
            Mp[r * 72 + n] = f2bf(CcArr[n] * __expf((float)(r + 1) * aArr[n]));
        }
#pragma unroll
        for (int i = 0; i < 16; ++i) {
            int s = seg + i;
            Tp[r * 72 + s] = (s <= r) ? f2bf(Kc[r - s]) : (ushort_t)0;
        }
        *(uint4*)(Up + r * 72 + seg)     = u01;
        *(uint4*)(Up + r * 72 + seg + 8) = u23;
    }
    __syncthreads();

    {
        int p0 = w * 16;
        f32x4 acc1[4] = {};
#pragma unroll
        for (int kk = 0; kk < 2; ++kk) {
            int koff = kk * 32 + (l >> 4) * 8;
            bf16x8 af = *(const bf16x8*)(Vp + (p0 + (l & 15)) * 72 + koff);
#pragma unroll
            for (int qt = 0; qt < 4; ++qt) {
                bf16x8 bf = *(const bf16x8*)(Up + (qt * 16 + (l & 15)) * 72 + koff);
                acc1[qt] = __builtin_amdgcn_mfma_f32_16x16x32_bf16(af, bf, acc1[qt], 0, 0, 0);
            }
        }
#pragma unroll
        for (int qt = 0; qt < 4; ++qt)
#pragma unroll
            for (int i = 0; i < 4; ++i)
                Wp[(qt * 16 + (l & 15)) * 68 + p0 + (l >> 4) * 4 + i] = acc1[qt][i];
    }
    __syncthreads();

    if (tid < 128) {
        int b2 = tid >> 6, n = tid & 63;
        float Ab64 = __expf(64.f * aArr[n]);
        float H = 0.f;
#pragma unroll
        for (int c = 0; c < 32; ++c) {
            int col = b2 * 32 + c;
            Hp[col * 72 + n] = f2bf(H);
            H = fmaf(Ab64, H, Wp[col * 68 + n]);
        }
    }
    __syncthreads();

    {
        int j0 = w * 16;
        f32x4 accY[4] = {};
#pragma unroll
        for (int kk = 0; kk < 2; ++kk) {
            int koff = kk * 32 + (l >> 4) * 8;
            bf16x8 at = *(const bf16x8*)(Tp + (j0 + (l & 15)) * 72 + koff);
            bf16x8 am = *(const bf16x8*)(Mp + (j0 + (l & 15)) * 72 + koff);
#pragma unroll
            for (int qt = 0; qt < 4; ++qt) {
                bf16x8 bu = *(const bf16x8*)(Up + (qt * 16 + (l & 15)) * 72 + koff);
                bf16x8 bh = *(const bf16x8*)(Hp + (qt * 16 + (l & 15)) * 72 + koff);
                accY[qt] = __builtin_amdgcn_mfma_f32_16x16x32_bf16(at, bu, accY[qt], 0, 0, 0);
                accY[qt] = __builtin_amdgcn_mfma_f32_16x16x32_bf16(am, bh, accY[qt], 0, 0, 0);
            }
        }
#pragma unroll
        for (int qt = 0; qt < 4; ++qt)
#pragma unroll
            for (int i = 0; i < 4; ++i)
                Wp[(qt * 16 + (l & 15)) * 68 + j0 + (l >> 4) * 4 + i] = accY[qt][i];
    }
    __syncthreads();

    {
        int col = tid >> 2, jseg = (tid & 3) * 16;
        int b3 = col >> 5, c3 = col & 31;
        ushort_t* dst = yTb + ((size_t)b3 * D_MODEL + d) * SEQ + c3 * 64 + jseg;
#pragma unroll
        for (int q = 0; q < 4; ++q) {
            f32x4 v = *(const f32x4*)(Wp + col * 68 + jseg + q * 4);
            ushort4 o = make_ushort4(f2bf(v.x), f2bf(v.y), f2bf(v.z), f2bf(v.w));
            *(ushort4*)(dst + q * 4) = o;
        }
    }
}

// ---------------- transpose: yTb bf16 [2][768][2048] -> yA bf16 [4096][768] ----------------
__global__ __launch_bounds__(256) void tcast_kernel(const ushort_t* __restrict__ yTb,
                                                    ushort_t* __restrict__ yA) {
    __shared__ float T2[64 * 68];
    int t = threadIdx.x;
    int s0 = blockIdx.x * 64, d0 = blockIdx.y * 64, b = blockIdx.z;
    int dl = t >> 2, sq = (t & 3) * 16;
    const ushort_t* src = yTb + ((size_t)b * D_MODEL + d0 + dl) * SEQ + s0 + sq;
    uint4 v01 = *(const uint4*)(src);
    uint4 v23 = *(const uint4*)(src + 8);
    const ushort_t* pv = (const ushort_t*)&v01;
#pragma unroll
    for (int j = 0; j < 8; ++j) T2[(sq + j) * 68 + dl] = bf2f(pv[j]);
    pv = (const ushort_t*)&v23;
#pragma unroll
    for (int j = 0; j < 8; ++j) T2[(sq + 8 + j) * 68 + dl] = bf2f(pv[j]);
    __syncthreads();
    int sl = t >> 2, dseg = (t & 3) * 16;
    ushort_t* dst = yA + ((size_t)(b * SEQ + s0 + sl)) * D_MODEL + d0 + dseg;
#pragma unroll
    for (int q = 0; q < 4; ++q) {
        float4 v = *(const float4*)&T2[sl * 68 + dseg + q * 4];
        ushort4 o = make_ushort4(f2bf(v.x), f2bf(v.y), f2bf(v.z), f2bf(v.w));
        *(ushort4*)(dst + q * 4) = o;
    }
}

extern "C" void kernel_launch(void* const* d_in, const int* in_sizes, int n_in,
                              void* d_out, int out_size, void* d_ws, size_t ws_size,
                              hipStream_t stream) {
    const float* x        = (const float*)d_in[0];
    const float* ln_gamma = (const float*)d_in[1];
    const float* ln_beta  = (const float*)d_in[2];
    const float* W_in     = (const float*)d_in[3];
    const float* b_in     = (const float*)d_in[4];
    const float* log_A    = (const float*)d_in[5];
    const float* B_p      = (const float*)d_in[6];
    const float* C_p      = (const float*)d_in[7];
    const float* D_p      = (const float*)d_in[8];
    const float* log_dt   = (const float*)d_in[9];
    const float* W_out    = (const float*)d_in[10];
    const float* b_out    = (const float*)d_in[11];
    float* out = (float*)d_out;

    char* ws = (char*)d_ws;
    ushort_t* uTb   = (ushort_t*)(ws + 0);                    // 6291456 B
    ushort_t* yTb   = (ushort_t*)(ws + 6291456);              // 6291456 B
    ushort_t* xnb   = (ushort_t*)(ws + 12582912);             // 6291456 B (reused as yA)
    ushort_t* yA    = xnb;
    ushort_t* Winb  = (ushort_t*)(ws + 18874368);             // 1179648 B
    ushort_t* Woutb = (ushort_t*)(ws + 20054016);             // 1179648 B

    pre_kernel<<<dim3(1024 + 1152), 256, 0, stream>>>(x, ln_gamma, ln_beta, xnb,
                                                      W_in, W_out, Winb, Woutb);
    gemm_in<<<dim3(M_TOTAL / 64, D_MODEL / 96), 256, 0, stream>>>(xnb, Winb, b_in, uTb);
    scan_mm<<<dim3(D_MODEL), 256, 0, stream>>>(uTb, log_A, B_p, C_p, D_p, log_dt, yTb);
    tcast_kernel<<<dim3(SEQ / 64, D_MODEL / 64, BATCH), 256, 0, stream>>>(yTb, yA);
    gemm_out<<<dim3(M_TOTAL / 64, D_MODEL / 96), 256, 0, stream>>>(yA, Woutb, b_out, x, out);
}

// Round 5
// 123.578 us; speedup vs baseline: 1.1024x; 1.0098x over previous
//
#include <hip/hip_runtime.h>
#include <math.h>

#define D_MODEL 768
#define D_STATE 64
#define BATCH   2
#define SEQ     2048
#define M_TOTAL (BATCH * SEQ)   // 4096

typedef unsigned short ushort_t;
typedef float f32x4 __attribute__((ext_vector_type(4)));
typedef __bf16 bf16x8 __attribute__((ext_vector_type(8)));

__device__ __forceinline__ ushort_t f2bf(float f) {
    unsigned u = __float_as_uint(f);
    u = (u + 0x7FFFu + ((u >> 16) & 1u)) >> 16;   // RNE
    return (ushort_t)u;
}

__device__ __forceinline__ void gload16(const void* g, void* shm) {
    __builtin_amdgcn_global_load_lds(
        (const __attribute__((address_space(1))) void*)g,
        (__attribute__((address_space(3))) void*)shm, 16, 0, 0);
}

// ---------------- fused pre-kernel: LayerNorm->bf16 (blocks 0..1023) + weight casts (blocks 1024..2175) ----------------
__global__ __launch_bounds__(256) void pre_kernel(const float* __restrict__ x,
                                                  const float* __restrict__ gamma,
                                                  const float* __restrict__ beta,
                                                  ushort_t* __restrict__ xnb,
                                                  const float* __restrict__ W_in,
                                                  const float* __restrict__ W_out,
                                                  ushort_t* __restrict__ Winb,
                                                  ushort_t* __restrict__ Woutb) {
    int bx = blockIdx.x;
    if (bx >= 1024) {
        int b2 = bx - 1024;                    // 0..1151
        const float* src = (b2 < 576) ? W_in : W_out;
        ushort_t*    dst = (b2 < 576) ? Winb : Woutb;
        int blk = (b2 < 576) ? b2 : b2 - 576;
        int i = (blk * 256 + threadIdx.x) * 4;
        float4 v = *(const float4*)(src + i);
        ushort4 o = make_ushort4(f2bf(v.x), f2bf(v.y), f2bf(v.z), f2bf(v.w));
        *(ushort4*)(dst + i) = o;
        return;
    }
    int row  = bx * 4 + (threadIdx.x >> 6);
    int lane = threadIdx.x & 63;
    const float* xr = x + (size_t)row * D_MODEL;
    float4 v[3];
    v[0] = *(const float4*)(xr + lane * 4);
    v[1] = *(const float4*)(xr + 256 + lane * 4);
    v[2] = *(const float4*)(xr + 512 + lane * 4);
    float s = 0.f, ss = 0.f;
#pragma unroll
    for (int i = 0; i < 3; ++i) {
        s  += v[i].x + v[i].y + v[i].z + v[i].w;
        ss += v[i].x * v[i].x + v[i].y * v[i].y + v[i].z * v[i].z + v[i].w * v[i].w;
    }
#pragma unroll
    for (int off = 1; off < 64; off <<= 1) {
        s  += __shfl_xor(s, off, 64);
        ss += __shfl_xor(ss, off, 64);
    }
    float mean = s * (1.0f / 768.0f);
    float var  = ss * (1.0f / 768.0f) - mean * mean;
    float inv  = 1.0f / sqrtf(var + 1e-5f);
    ushort_t* xo = xnb + (size_t)row * D_MODEL;
#pragma unroll
    for (int i = 0; i < 3; ++i) {
        int c = i * 256 + lane * 4;
        float4 g  = *(const float4*)(gamma + c);
        float4 bb = *(const float4*)(beta + c);
        ushort4 o = make_ushort4(f2bf((v[i].x - mean) * inv * g.x + bb.x),
                                 f2bf((v[i].y - mean) * inv * g.y + bb.y),
                                 f2bf((v[i].z - mean) * inv * g.z + bb.z),
                                 f2bf((v[i].w - mean) * inv * g.w + bb.w));
        *(ushort4*)(xo + c) = o;
    }
}

// ---------------- bf16 MFMA GEMM, 64x96 tile, BK=64, double-buffered 2-phase ----------------
// (R3-verified structure.) LDS rows = 128 B (8 segs of 16B), seg sg of row r at
// slot (sg ^ (r&7)); A buffers 2x8KB @0, B buffers 2x12KB @16K = 40960B.

// gemm_in: u = xn @ W_in^T + b_in -> uTb bf16 [b][n][s] (LDS-transposed epilogue)
__global__ __launch_bounds__(256) void gemm_in(const ushort_t* __restrict__ A,   // xn bf16 [4096][768]
                                               const ushort_t* __restrict__ B,   // W_in bf16 [768][768]
                                               const float* __restrict__ bias,
                                               ushort_t* __restrict__ uTb) {     // bf16 [2][768][2048]
    __shared__ __align__(16) char smem[40960];
    float* T = (float*)smem;                 // epilogue alias (96x68 fp32 = 26112 B)

    int tid = threadIdx.x;
    int w = tid >> 6, l = tid & 63;
    int bm = blockIdx.x * 64, bn = blockIdx.y * 96;
    int wr = w >> 1, wc = w & 1;

    int lr = l >> 3;                  // staging sub-row 0..7
    int scol0 = ((l & 7) ^ lr) * 8;   // pre-swizzled k-offset

    float biasv[3];
#pragma unroll
    for (int nt = 0; nt < 3; ++nt)
        biasv[nt] = bias[bn + wc * 48 + nt * 16 + (l & 15)];

    char* Acur = smem;          char* Aalt = smem + 8192;
    char* Bcur = smem + 16384;  char* Balt = smem + 28672;

    // prologue: stage tile 0
#pragma unroll
    for (int q = 0; q < 2; ++q) {
        int row = w * 16 + q * 8 + lr;
        gload16(A + (size_t)(bm + row) * D_MODEL + scol0, Acur + w * 2048 + q * 1024);
    }
#pragma unroll
    for (int q = 0; q < 3; ++q) {
        int row = w * 24 + q * 8 + lr;
        gload16(B + (size_t)(bn + row) * D_MODEL + scol0, Bcur + w * 3072 + q * 1024);
    }
    __syncthreads();

    f32x4 acc[2][3] = {};
    for (int t = 0; t < 12; ++t) {
        if (t < 11) {
            int k1 = (t + 1) * 64;
#pragma unroll
            for (int q = 0; q < 2; ++q) {
                int row = w * 16 + q * 8 + lr;
                gload16(A + (size_t)(bm + row) * D_MODEL + k1 + scol0, Aalt + w * 2048 + q * 1024);
            }
#pragma unroll
            for (int q = 0; q < 3; ++q) {
                int row = w * 24 + q * 8 + lr;
                gload16(B + (size_t)(bn + row) * D_MODEL + k1 + scol0, Balt + w * 3072 + q * 1024);
            }
        }
#pragma unroll
        for (int kk = 0; kk < 2; ++kk) {
            int sgb = kk * 4 + (l >> 4);
            bf16x8 af[2], bfr[3];
#pragma unroll
            for (int mt = 0; mt < 2; ++mt) {
                int r = wr * 32 + mt * 16 + (l & 15);
                af[mt] = *(const bf16x8*)(Acur + r * 128 + ((sgb ^ (r & 7)) * 16));
            }
#pragma unroll
            for (int nt = 0; nt < 3; ++nt) {
                int r = wc * 48 + nt * 16 + (l & 15);
                bfr[nt] = *(const bf16x8*)(Bcur + r * 128 + ((sgb ^ (r & 7)) * 16));
            }
#pragma unroll
            for (int mt = 0; mt < 2; ++mt)
#pragma unroll
                for (int nt = 0; nt < 3; ++nt)
                    acc[mt][nt] = __builtin_amdgcn_mfma_f32_16x16x32_bf16(af[mt], bfr[nt], acc[mt][nt], 0, 0, 0);
        }
        __syncthreads();
        char* t1 = Acur; Acur = Aalt; Aalt = t1;
        t1 = Bcur; Bcur = Balt; Balt = t1;
    }

    // epilogue: LDS transpose -> uTb[b][n][s] bf16 coalesced
#pragma unroll
    for (int mt = 0; mt < 2; ++mt)
#pragma unroll
        for (int nt = 0; nt < 3; ++nt)
#pragma unroll
            for (int i = 0; i < 4; ++i) {
                int nl = wc * 48 + nt * 16 + (l & 15);
                int ml = wr * 32 + mt * 16 + (l >> 4) * 4 + i;
                T[nl * 68 + ml] = acc[mt][nt][i] + biasv[nt];
            }
    __syncthreads();
    int b = bm >> 11, sbase = bm & 2047;
    for (int t2 = tid; t2 < 384; t2 += 256) {
        int n2 = t2 >> 2, m0 = (t2 & 3) * 16;
        ushort_t* dst = uTb + ((size_t)b * D_MODEL + bn + n2) * SEQ + sbase + m0;
#pragma unroll
        for (int q = 0; q < 4; ++q) {
            float4 v = *(const float4*)&T[n2 * 68 + m0 + q * 4];
            ushort4 o = make_ushort4(f2bf(v.x), f2bf(v.y), f2bf(v.z), f2bf(v.w));
            *(ushort4*)(dst + q * 4) = o;
        }
    }
}

// gemm_out FUSED with transpose: A operand read directly from yTb [2][768][2048].
// Per K-step the 64(s)x64(d) y-tile is reg-staged (2x uint4 along s for a d-pair)
// and ds_write_b32-transposed into the swizzled A layout. T14 split: global reads
// issued BEFORE the current tile's MFMAs, LDS writes after. W_out staging stays
// global_load_lds double-buffered. Removes the tcast kernel entirely.
__global__ __launch_bounds__(256) void gemm_out(const ushort_t* __restrict__ Y,   // yTb bf16 [2][768][2048]
                                                const ushort_t* __restrict__ B,   // W_out bf16 [768][768]
                                                const float* __restrict__ bias,
                                                const float* __restrict__ resid,
                                                float* __restrict__ out) {
    __shared__ __align__(16) char smem[40960];
    int tid = threadIdx.x;
    int w = tid >> 6, l = tid & 63;
    int bm = blockIdx.x * 64, bn = blockIdx.y * 96;
    int wr = w >> 1, wc = w & 1;

    int bb = bm >> 11, sbase = bm & 2047;   // batch, seq-base of this m-tile

    int lr = l >> 3;
    int scol0 = ((l & 7) ^ lr) * 8;

    // transpose-staging coords: each thread owns a d-pair x 8 s
    int d0 = (tid & 31) * 2;       // 0..62 (even)
    int sq = (tid >> 5) * 8;       // 0..56
    int segd = d0 >> 3;
    int dby = (d0 & 7) * 2;

    float biasv[3];
#pragma unroll
    for (int nt = 0; nt < 3; ++nt)
        biasv[nt] = bias[bn + wc * 48 + nt * 16 + (l & 15)];

    char* Acur = smem;          char* Aalt = smem + 8192;
    char* Bcur = smem + 16384;  char* Balt = smem + 28672;

    // prologue: stage tile 0 (y via reg-transpose, W via gload16)
    {
        const ushort_t* yrow = Y + ((size_t)bb * D_MODEL + d0) * SEQ + sbase + sq;
        uint4 r0 = *(const uint4*)(yrow);
        uint4 r1 = *(const uint4*)(yrow + SEQ);
        const ushort_t* p0 = (const ushort_t*)&r0;
        const ushort_t* p1 = (const ushort_t*)&r1;
#pragma unroll
        for (int i = 0; i < 8; ++i) {
            int s = sq + i;
            unsigned pk = (unsigned)p0[i] | ((unsigned)p1[i] << 16);
            *(unsigned*)(Acur + s * 128 + ((segd ^ (s & 7)) * 16) + dby) = pk;
        }
#pragma unroll
        for (int q = 0; q < 3; ++q) {
            int row = w * 24 + q * 8 + lr;
            gload16(B + (size_t)(bn + row) * D_MODEL + scol0, Bcur + w * 3072 + q * 1024);
        }
    }
    __syncthreads();

    f32x4 acc[2][3] = {};
    for (int t = 0; t < 12; ++t) {
        uint4 r0, r1;
        if (t < 11) {
            int k1 = (t + 1) * 64;
            const ushort_t* yrow = Y + ((size_t)bb * D_MODEL + k1 + d0) * SEQ + sbase + sq;
            r0 = *(const uint4*)(yrow);            // issue early (T14)
            r1 = *(const uint4*)(yrow + SEQ);
#pragma unroll
            for (int q = 0; q < 3; ++q) {
                int row = w * 24 + q * 8 + lr;
                gload16(B + (size_t)(bn + row) * D_MODEL + k1 + scol0, Balt + w * 3072 + q * 1024);
            }
        }
#pragma unroll
        for (int kk = 0; kk < 2; ++kk) {
            int sgb = kk * 4 + (l >> 4);
            bf16x8 af[2], bfr[3];
#pragma unroll
            for (int mt = 0; mt < 2; ++mt) {
                int r = wr * 32 + mt * 16 + (l & 15);
                af[mt] = *(const bf16x8*)(Acur + r * 128 + ((sgb ^ (r & 7)) * 16));
            }
#pragma unroll
            for (int nt = 0; nt < 3; ++nt) {
                int r = wc * 48 + nt * 16 + (l & 15);
                bfr[nt] = *(const bf16x8*)(Bcur + r * 128 + ((sgb ^ (r & 7)) * 16));
            }
#pragma unroll
            for (int mt = 0; mt < 2; ++mt)
#pragma unroll
                for (int nt = 0; nt < 3; ++nt)
                    acc[mt][nt] = __builtin_amdgcn_mfma_f32_16x16x32_bf16(af[mt], bfr[nt], acc[mt][nt], 0, 0, 0);
        }
        if (t < 11) {                              // write late (T14)
            const ushort_t* p0 = (const ushort_t*)&r0;
            const ushort_t* p1 = (const ushort_t*)&r1;
#pragma unroll
            for (int i = 0; i < 8; ++i) {
                int s = sq + i;
                unsigned pk = (unsigned)p0[i] | ((unsigned)p1[i] << 16);
                *(unsigned*)(Aalt + s * 128 + ((segd ^ (s & 7)) * 16) + dby) = pk;
            }
        }
        __syncthreads();
        char* t1 = Acur; Acur = Aalt; Aalt = t1;
        t1 = Bcur; Bcur = Balt; Balt = t1;
    }

#pragma unroll
    for (int mt = 0; mt < 2; ++mt)
#pragma unroll
        for (int i = 0; i < 4; ++i) {
            int m = bm + wr * 32 + mt * 16 + (l >> 4) * 4 + i;
            const float* rp = resid + (size_t)m * D_MODEL + bn;
            float* op = out + (size_t)m * D_MODEL + bn;
#pragma unroll
            for (int nt = 0; nt < 3; ++nt) {
                int nl = wc * 48 + nt * 16 + (l & 15);
                op[nl] = acc[mt][nt][i] + biasv[nt] + rp[nl];
            }
        }
}

// ---------------- scan as blocked matmuls (SSD-style) ----------------
#define OFF_U  0
#define OFF_V  9216
#define OFF_T  18432
#define OFF_M  27648
#define OFF_H  36864
#define OFF_W  46080
#define OFF_SM 63488

__global__ __launch_bounds__(256) void scan_mm(const ushort_t* __restrict__ uTb,
                                               const float* __restrict__ log_A,
                                               const float* __restrict__ B_p,
                                               const float* __restrict__ C_p,
                                               const float* __restrict__ D_p,
                                               const float* __restrict__ log_dt,
                                               ushort_t* __restrict__ yTb) {
    __shared__ __align__(16) char smem[65024];
    ushort_t* Up = (ushort_t*)(smem + OFF_U);
    ushort_t* Vp = (ushort_t*)(smem + OFF_V);
    ushort_t* Tp = (ushort_t*)(smem + OFF_T);
    ushort_t* Mp = (ushort_t*)(smem + OFF_M);
    ushort_t* Hp = (ushort_t*)(smem + OFF_H);
    float*    Wp = (float*)(smem + OFF_W);
    float*    Kp = (float*)(smem + OFF_W);
    float*    aArr  = (float*)(smem + OFF_SM);
    float*    BbArr = aArr + 64;
    float*    CcArr = aArr + 128;
    float*    CBArr = aArr + 192;
    float*    Kc    = aArr + 256;

    int d   = blockIdx.x;
    int tid = threadIdx.x;
    int w   = tid >> 6, l = tid & 63;

    // T14 issue-early: U global loads issued at kernel top
    int r_pre = tid >> 2, seg_pre = (tid & 3) * 16;
    int bu_pre = r_pre >> 5, cu_pre = r_pre & 31;
    const ushort_t* usrc = uTb + ((size_t)bu_pre * D_MODEL + d) * SEQ + cu_pre * 64 + seg_pre;
    uint4 u01 = *(const uint4*)(usrc);
    uint4 u23 = *(const uint4*)(usrc + 8);

    if (tid < 64) {
        int n = tid;
        float dt = __expf(log_dt[d]);
        float a  = -dt * __expf(log_A[d * 64 + n]);
        float Bb = B_p[d * 64 + n] * dt;
        float Cc = C_p[d * 64 + n];
        aArr[n] = a; BbArr[n] = Bb; CcArr[n] = Cc; CBArr[n] = Cc * Bb;
    }
    __syncthreads();

    {
        int tau = tid & 63, part = tid >> 6;
        float s = 0.f;
#pragma unroll
        for (int i = 0; i < 16; ++i) {
            int n = part * 16 + i;
            s += CBArr[n] * __expf((float)tau * aArr[n]);
        }
        Kp[part * 64 + tau] = s;
    }
    __syncthreads();
    if (tid < 64)
        Kc[tid] = Kp[tid] + Kp[64 + tid] + Kp[128 + tid] + Kp[192 + tid]
                + (tid == 0 ? D_p[d] : 0.f);
    __syncthreads();

    {
        int r = tid >> 2, seg = (tid & 3) * 16;
        float a = aArr[r], Bb = BbArr[r];
#pragma unroll
        for (int i = 0; i < 16; ++i) {
            int s = seg + i;
            Vp[r * 72 + s] = f2bf(Bb * __expf((float)(63 - s) * a));
        }
#pragma unroll
        for (int i = 0; i < 16; ++i) {
            int n = seg + i;
            Mp[r * 72 + n] = f2bf(CcArr[n] * __expf((float)(r + 1) * aArr[n]));
        }
#pragma unroll
        for (int i = 0; i < 16; ++i) {
            int s = seg + i;
            Tp[r * 72 + s] = (s <= r) ? f2bf(Kc[r - s]) : (ushort_t)0;
        }
        *(uint4*)(Up + r * 72 + seg)     = u01;
        *(uint4*)(Up + r * 72 + seg + 8) = u23;
    }
    __syncthreads();

    {
        int p0 = w * 16;
        f32x4 acc1[4] = {};
#pragma unroll
        for (int kk = 0; kk < 2; ++kk) {
            int koff = kk * 32 + (l >> 4) * 8;
            bf16x8 af = *(const bf16x8*)(Vp + (p0 + (l & 15)) * 72 + koff);
#pragma unroll
            for (int qt = 0; qt < 4; ++qt) {
                bf16x8 bf = *(const bf16x8*)(Up + (qt * 16 + (l & 15)) * 72 + koff);
                acc1[qt] = __builtin_amdgcn_mfma_f32_16x16x32_bf16(af, bf, acc1[qt], 0, 0, 0);
            }
        }
#pragma unroll
        for (int qt = 0; qt < 4; ++qt)
#pragma unroll
            for (int i = 0; i < 4; ++i)
                Wp[(qt * 16 + (l & 15)) * 68 + p0 + (l >> 4) * 4 + i] = acc1[qt][i];
    }
    __syncthreads();

    if (tid < 128) {
        int b2 = tid >> 6, n = tid & 63;
        float Ab64 = __expf(64.f * aArr[n]);
        float H = 0.f;
#pragma unroll
        for (int c = 0; c < 32; ++c) {
            int col = b2 * 32 + c;
            Hp[col * 72 + n] = f2bf(H);
            H = fmaf(Ab64, H, Wp[col * 68 + n]);
        }
    }
    __syncthreads();

    {
        int j0 = w * 16;
        f32x4 accY[4] = {};
#pragma unroll
        for (int kk = 0; kk < 2; ++kk) {
            int koff = kk * 32 + (l >> 4) * 8;
            bf16x8 at = *(const bf16x8*)(Tp + (j0 + (l & 15)) * 72 + koff);
            bf16x8 am = *(const bf16x8*)(Mp + (j0 + (l & 15)) * 72 + koff);
#pragma unroll
            for (int qt = 0; qt < 4; ++qt) {
                bf16x8 bu = *(const bf16x8*)(Up + (qt * 16 + (l & 15)) * 72 + koff);
                bf16x8 bh = *(const bf16x8*)(Hp + (qt * 16 + (l & 15)) * 72 + koff);
                accY[qt] = __builtin_amdgcn_mfma_f32_16x16x32_bf16(at, bu, accY[qt], 0, 0, 0);
                accY[qt] = __builtin_amdgcn_mfma_f32_16x16x32_bf16(am, bh, accY[qt], 0, 0, 0);
            }
        }
#pragma unroll
        for (int qt = 0; qt < 4; ++qt)
#pragma unroll
            for (int i = 0; i < 4; ++i)
                Wp[(qt * 16 + (l & 15)) * 68 + j0 + (l >> 4) * 4 + i] = accY[qt][i];
    }
    __syncthreads();

    {
        int col = tid >> 2, jseg = (tid & 3) * 16;
        int b3 = col >> 5, c3 = col & 31;
        ushort_t* dst = yTb + ((size_t)b3 * D_MODEL + d) * SEQ + c3 * 64 + jseg;
#pragma unroll
        for (int q = 0; q < 4; ++q) {
            f32x4 v = *(const f32x4*)(Wp + col * 68 + jseg + q * 4);
            ushort4 o = make_ushort4(f2bf(v.x), f2bf(v.y), f2bf(v.z), f2bf(v.w));
            *(ushort4*)(dst + q * 4) = o;
        }
    }
}

extern "C" void kernel_launch(void* const* d_in, const int* in_sizes, int n_in,
                              void* d_out, int out_size, void* d_ws, size_t ws_size,
                              hipStream_t stream) {
    const float* x        = (const float*)d_in[0];
    const float* ln_gamma = (const float*)d_in[1];
    const float* ln_beta  = (const float*)d_in[2];
    const float* W_in     = (const float*)d_in[3];
    const float* b_in     = (const float*)d_in[4];
    const float* log_A    = (const float*)d_in[5];
    const float* B_p      = (const float*)d_in[6];
    const float* C_p      = (const float*)d_in[7];
    const float* D_p      = (const float*)d_in[8];
    const float* log_dt   = (const float*)d_in[9];
    const float* W_out    = (const float*)d_in[10];
    const float* b_out    = (const float*)d_in[11];
    float* out = (float*)d_out;

    char* ws = (char*)d_ws;
    ushort_t* uTb   = (ushort_t*)(ws + 0);                    // 6291456 B
    ushort_t* yTb   = (ushort_t*)(ws + 6291456);              // 6291456 B
    ushort_t* xnb   = (ushort_t*)(ws + 12582912);             // 6291456 B
    ushort_t* Winb  = (ushort_t*)(ws + 18874368);             // 1179648 B
    ushort_t* Woutb = (ushort_t*)(ws + 20054016);             // 1179648 B

    pre_kernel<<<dim3(1024 + 1152), 256, 0, stream>>>(x, ln_gamma, ln_beta, xnb,
                                                      W_in, W_out, Winb, Woutb);
    gemm_in<<<dim3(M_TOTAL / 64, D_MODEL / 96), 256, 0, stream>>>(xnb, Winb, b_in, uTb);
    scan_mm<<<dim3(D_MODEL), 256, 0, stream>>>(uTb, log_A, B_p, C_p, D_p, log_dt, yTb);
    gemm_out<<<dim3(M_TOTAL / 64, D_MODEL / 96), 256, 0, stream>>>(yTb, Woutb, b_out, x, out);
}